// Round 1
// baseline (2432.989 us; speedup 1.0000x reference)
//
#include <hip/hip_runtime.h>
#include <math.h>

#define B_ROWS   1024
#define DIM      192
#define NCLS     100000
#define S_SCALE  30.0f
#define COS_M    0.98006657784124163f
#define SIN_M    0.19866933079506122f
#define TH_C     (-0.98006657784124163f)
#define MM_C     0.039733866159012243f

// GEMM+stats tiling
#define KB_ROWS     64     // rows per block
#define KB_COLS     128    // cols per subtile
#define KB_SUBT     4      // subtiles per block -> 512 classes/block
#define CB_CLASSES  512
#define NUM_CB      196    // 196*512 = 100352 >= 100000
#define ASTRIDE     196    // padded LDS row stride (floats), 16B aligned, conflict-free

// ---------------------------------------------------------------------------
// Kernel A: row L2 norms. Writes x_normalized and 1/||w_c||.
// One wave (64 lanes) per row; lanes 0..47 each own one float4 of the 192.
// ---------------------------------------------------------------------------
__global__ __launch_bounds__(256)
void norm_kernel(const float* __restrict__ x, const float* __restrict__ w,
                 float* __restrict__ xn, float* __restrict__ winv)
{
    const int wid  = blockIdx.x * 4 + (threadIdx.x >> 6);
    const int lane = threadIdx.x & 63;
    if (wid < B_ROWS) {
        const float* src = x + (size_t)wid * DIM;
        float4 v = make_float4(0.f, 0.f, 0.f, 0.f);
        float s = 0.f;
        if (lane < 48) {
            v = ((const float4*)src)[lane];
            s = v.x * v.x + v.y * v.y + v.z * v.z + v.w * v.w;
        }
        #pragma unroll
        for (int off = 32; off > 0; off >>= 1) s += __shfl_xor(s, off);
        float inv = 1.0f / fmaxf(sqrtf(s), 1e-12f);
        if (lane < 48) {
            float4 o;
            o.x = v.x * inv; o.y = v.y * inv; o.z = v.z * inv; o.w = v.w * inv;
            ((float4*)(xn + (size_t)wid * DIM))[lane] = o;
        }
    } else if (wid < B_ROWS + NCLS) {
        const int c = wid - B_ROWS;
        const float* src = w + (size_t)c * DIM;
        float s = 0.f;
        if (lane < 48) {
            float4 v = ((const float4*)src)[lane];
            s = v.x * v.x + v.y * v.y + v.z * v.z + v.w * v.w;
        }
        #pragma unroll
        for (int off = 32; off > 0; off >>= 1) s += __shfl_xor(s, off);
        if (lane == 0) winv[c] = 1.0f / fmaxf(sqrtf(s), 1e-12f);
    }
}

// ---------------------------------------------------------------------------
// Kernel B: fused GEMM + per-row online-softmax stats + top-2 over a
// 64-row x 512-class block. Writes one partial (m, l, v1, v2, i1) per
// (class-block, row).
// ---------------------------------------------------------------------------
__global__ __launch_bounds__(256, 2)
void gemm_stats_kernel(const float* __restrict__ xn, const float* __restrict__ w,
                       const float* __restrict__ winv,
                       float* __restrict__ pm, float* __restrict__ pl,
                       float* __restrict__ pv1, float* __restrict__ pv2,
                       int* __restrict__ pi1)
{
    __shared__ float As[KB_ROWS * ASTRIDE];   // 50176 B -> 2 blocks/CU
    const int tid = threadIdx.x;
    const int tx = tid & 15;        // column group
    const int ty = tid >> 4;        // row group
    const int rowBase = blockIdx.y * KB_ROWS;
    const int cb = blockIdx.x;

    // Stage A tile: 64 rows x 192 floats (coalesced float4 loads)
    for (int t4 = tid; t4 < KB_ROWS * 48; t4 += 256) {
        int r  = t4 / 48;
        int kk = (t4 % 48) * 4;
        float4 v = *(const float4*)(xn + (size_t)(rowBase + r) * DIM + kk);
        *(float4*)(&As[r * ASTRIDE + kk]) = v;
    }
    __syncthreads();

    // Per-row stats (rows r = ty + 16*i)
    float m_[4], l_[4], v1_[4], v2_[4];
    int i1_[4];
    #pragma unroll
    for (int i = 0; i < 4; ++i) {
        m_[i] = -INFINITY; l_[i] = 0.f; v1_[i] = -INFINITY; v2_[i] = -INFINITY; i1_[i] = -1;
    }

    for (int sub = 0; sub < KB_SUBT; ++sub) {
        const int colBase = cb * CB_CLASSES + sub * KB_COLS;
        const float* wp[8];
        int cj_[8];
        bool valid[8];
        #pragma unroll
        for (int j = 0; j < 8; ++j) {
            int cj = colBase + tx + 16 * j;
            cj_[j] = cj;
            valid[j] = (cj < NCLS);
            wp[j] = w + (size_t)(valid[j] ? cj : 0) * DIM;
        }

        float acc[4][8];
        #pragma unroll
        for (int i = 0; i < 4; ++i)
            #pragma unroll
            for (int j = 0; j < 8; ++j) acc[i][j] = 0.f;

        #pragma unroll 4
        for (int kc = 0; kc < 48; ++kc) {
            float4 b[8];
            #pragma unroll
            for (int j = 0; j < 8; ++j) b[j] = *(const float4*)(wp[j] + kc * 4);
            #pragma unroll
            for (int i = 0; i < 4; ++i) {
                float4 a = *(const float4*)(&As[(ty + 16 * i) * ASTRIDE + kc * 4]);
                #pragma unroll
                for (int j = 0; j < 8; ++j) {
                    acc[i][j] += a.x * b[j].x;
                    acc[i][j] += a.y * b[j].y;
                    acc[i][j] += a.z * b[j].z;
                    acc[i][j] += a.w * b[j].w;
                }
            }
        }

        // Epilogue: logits + online stats
        #pragma unroll
        for (int j = 0; j < 8; ++j) {
            if (!valid[j]) continue;
            float wi = winv[cj_[j]];
            #pragma unroll
            for (int i = 0; i < 4; ++i) {
                float v = acc[i][j] * wi * S_SCALE;
                if (v > v1_[i]) { v2_[i] = v1_[i]; v1_[i] = v; i1_[i] = cj_[j]; }
                else if (v > v2_[i]) { v2_[i] = v; }
                if (v > m_[i]) { l_[i] = l_[i] * __expf(m_[i] - v) + 1.f; m_[i] = v; }
                else           { l_[i] += __expf(v - m_[i]); }
            }
        }
    }

    // Cross-thread (tx) reduction per row via LDS (alias onto As)
    __syncthreads();
    float* red = As;   // need 64*16*5 = 5120 floats <= 12544 available
    #pragma unroll
    for (int i = 0; i < 4; ++i) {
        int r = ty + 16 * i;
        float* p = red + (r * 16 + tx) * 5;
        p[0] = m_[i]; p[1] = l_[i]; p[2] = v1_[i]; p[3] = v2_[i];
        p[4] = __int_as_float(i1_[i]);
    }
    __syncthreads();
    if (tid < KB_ROWS) {
        const int r = tid;
        float M = -INFINITY, L = 0.f, V1 = -INFINITY, V2 = -INFINITY;
        int I1 = -1;
        for (int t = 0; t < 16; ++t) {
            const float* p = red + (r * 16 + t) * 5;
            float mb = p[0], lb = p[1], vb1 = p[2], vb2 = p[3];
            int ib1 = __float_as_int(p[4]);
            if (mb != -INFINITY) {
                if (mb > M) { L = L * __expf(M - mb) + lb; M = mb; }
                else        { L += lb * __expf(mb - M); }
            }
            if (vb1 > V1) { V2 = fmaxf(V1, vb2); V1 = vb1; I1 = ib1; }
            else          { V2 = fmaxf(V2, vb1); }
        }
        const int gi = cb * B_ROWS + rowBase + r;
        pm[gi] = M; pl[gi] = L; pv1[gi] = V1; pv2[gi] = V2; pi1[gi] = I1;
    }
}

// ---------------------------------------------------------------------------
// Kernel C: per-row merge of 196 partials + label-logit margin correction.
// 16 blocks x 64 threads (one wave per block), one row per thread.
// ---------------------------------------------------------------------------
__global__ __launch_bounds__(64)
void finalize_kernel(const float* __restrict__ xn, const float* __restrict__ w,
                     const float* __restrict__ winv, const int* __restrict__ label,
                     const float* __restrict__ pm, const float* __restrict__ pl,
                     const float* __restrict__ pv1, const float* __restrict__ pv2,
                     const int* __restrict__ pi1, float* __restrict__ accum)
{
    const int r = blockIdx.x * 64 + threadIdx.x;
    float M = -INFINITY, L = 0.f, V1 = -INFINITY, V2 = -INFINITY;
    int I1 = -1;
    for (int cbi = 0; cbi < NUM_CB; ++cbi) {
        const int gi = cbi * B_ROWS + r;
        float mb = pm[gi], lb = pl[gi], vb1 = pv1[gi], vb2 = pv2[gi];
        int ib1 = pi1[gi];
        if (mb != -INFINITY) {
            if (mb > M) { L = L * __expf(M - mb) + lb; M = mb; }
            else        { L += lb * __expf(mb - M); }
        }
        if (vb1 > V1) { V2 = fmaxf(V1, vb2); V1 = vb1; I1 = ib1; }
        else          { V2 = fmaxf(V2, vb1); }
    }

    const int lab = label[r];
    const float4* xr = (const float4*)(xn + (size_t)r * DIM);
    const float4* wr = (const float4*)(w + (size_t)lab * DIM);
    float dot = 0.f;
    #pragma unroll
    for (int q = 0; q < 48; ++q) {
        float4 a = xr[q], b = wr[q];
        dot += a.x * b.x + a.y * b.y + a.z * b.z + a.w * b.w;
    }
    float cosl    = dot * winv[lab];
    float t_plain = S_SCALE * cosl;
    float sine    = sqrtf(fmaxf(0.f, fminf(1.f, 1.f - cosl * cosl)));
    float phi     = cosl * COS_M - sine * SIN_M;
    float modv    = ((cosl - TH_C) > 0.f) ? phi : (cosl - MM_C);
    float t_mod   = S_SCALE * modv;

    // replace plain label term with modified one in the sum-exp
    float Ladj = L - expf(t_plain - M) + expf(t_mod - M);
    Ladj = fmaxf(Ladj, 1e-30f);
    float lse  = M + logf(Ladj);
    float loss = lse - t_mod;
    // pred == label iff label was plain argmax AND modified value still beats #2
    float corr = (I1 == lab && t_mod > V2) ? 1.f : 0.f;

    #pragma unroll
    for (int off = 32; off > 0; off >>= 1) {
        loss += __shfl_xor(loss, off);
        corr += __shfl_xor(corr, off);
    }
    if (threadIdx.x == 0) {
        atomicAdd(&accum[0], loss);
        atomicAdd(&accum[1], corr);
    }
}

__global__ void writeout_kernel(const float* __restrict__ accum, float* __restrict__ out)
{
    out[0] = accum[0] * (1.0f / (float)B_ROWS);
    out[1] = accum[1] * (100.0f / (float)B_ROWS);
}

// ---------------------------------------------------------------------------
extern "C" void kernel_launch(void* const* d_in, const int* in_sizes, int n_in,
                              void* d_out, int out_size, void* d_ws, size_t ws_size,
                              hipStream_t stream)
{
    const float* x     = (const float*)d_in[0];
    const float* w     = (const float*)d_in[1];
    const int*   label = (const int*)d_in[2];
    float* out = (float*)d_out;

    char* ws = (char*)d_ws;
    float* accum = (float*)ws;                         // 2 floats (256 B slot)
    float* xn    = (float*)(ws + 256);                 // 1024*192*4 = 786432 B
    float* winv  = (float*)(ws + 256 + 786432);        // 100000*4 -> pad 400128 B
    size_t off = 256 + 786432 + 400128;
    const size_t PSZ = (size_t)NUM_CB * B_ROWS * 4;    // 802816 B each
    float* pm  = (float*)(ws + off); off += PSZ;
    float* pl  = (float*)(ws + off); off += PSZ;
    float* pv1 = (float*)(ws + off); off += PSZ;
    float* pv2 = (float*)(ws + off); off += PSZ;
    int*   pi1 = (int*)  (ws + off); off += PSZ;

    hipMemsetAsync(accum, 0, 2 * sizeof(float), stream);

    norm_kernel<<<dim3((B_ROWS + NCLS + 3) / 4), dim3(256), 0, stream>>>(x, w, xn, winv);
    gemm_stats_kernel<<<dim3(NUM_CB, B_ROWS / KB_ROWS), dim3(256), 0, stream>>>(
        xn, w, winv, pm, pl, pv1, pv2, pi1);
    finalize_kernel<<<dim3(B_ROWS / 64), dim3(64), 0, stream>>>(
        xn, w, winv, label, pm, pl, pv1, pv2, pi1, accum);
    writeout_kernel<<<dim3(1), dim3(1), 0, stream>>>(accum, out);
}

// Round 2
// 298.453 us; speedup vs baseline: 8.1520x; 8.1520x over previous
//
#include <hip/hip_runtime.h>
#include <math.h>

#define B_ROWS   1024
#define DIM      192
#define NCLS     100000
#define NCLS_PAD 100352
#define S_SCALE  30.0f
#define COS_M    0.98006657784124163f
#define SIN_M    0.19866933079506122f
#define TH_C     (-0.98006657784124163f)
#define MM_C     0.039733866159012243f
#define NEG_BIG  (-3.0e38f)

#define BM 128
#define BN 128
#define NTILE 784          // class tiles of 128 -> 100352
#define NCHUNK 1568        // 64-col chunks (2 per tile)
#define NGRP 16
#define CCPG 98            // chunks merged per group (16*98 = 1568)

typedef float floatx4 __attribute__((ext_vector_type(4)));
typedef __bf16 bf16x8 __attribute__((ext_vector_type(8)));

__device__ __forceinline__ unsigned short f2bf(float x) {
    unsigned int u = __float_as_uint(x);
    u = (u + 0x7fffu + ((u >> 16) & 1u)) >> 16;   // RNE
    return (unsigned short)u;
}

__device__ __forceinline__ void gll16(const void* g, void* l) {
    __builtin_amdgcn_global_load_lds(
        (const __attribute__((address_space(1))) unsigned int*)g,
        (__attribute__((address_space(3))) unsigned int*)l, 16, 0, 0);
}

// merge partial (m, l, v2, idx) into running stats
__device__ __forceinline__ void merge_stats(float& M, float& L, float& V2, int& I, float4 p)
{
    float mb = p.x, lb = p.y, vb2 = p.z;
    int ib = __float_as_int(p.w);
    float nv2 = fmaxf(fminf(M, mb), fmaxf(V2, vb2));
    if (mb > M) { L = L * __expf(M - mb) + lb; M = mb; I = ib; }
    else        { L = L + lb * __expf(mb - M); }
    V2 = nv2;
}

// ---------------------------------------------------------------------------
// Prep: normalize x -> xnf (fp32) + xnb (bf16); normalize w -> wnb (bf16,
// padded rows zeroed) + winv (fp32). One wave per row.
// ---------------------------------------------------------------------------
__global__ __launch_bounds__(256)
void prep_kernel(const float* __restrict__ x, const float* __restrict__ w,
                 float* __restrict__ xnf, unsigned short* __restrict__ xnb,
                 unsigned short* __restrict__ wnb, float* __restrict__ winv)
{
    const int wid  = blockIdx.x * 4 + (threadIdx.x >> 6);
    const int lane = threadIdx.x & 63;
    if (wid < B_ROWS) {
        const float* src = x + (size_t)wid * DIM;
        float4 v = make_float4(0.f, 0.f, 0.f, 0.f);
        float s = 0.f;
        if (lane < 48) {
            v = ((const float4*)src)[lane];
            s = v.x * v.x + v.y * v.y + v.z * v.z + v.w * v.w;
        }
        #pragma unroll
        for (int off = 32; off > 0; off >>= 1) s += __shfl_xor(s, off);
        float inv = 1.0f / fmaxf(sqrtf(s), 1e-12f);
        if (lane < 48) {
            float4 o = make_float4(v.x * inv, v.y * inv, v.z * inv, v.w * inv);
            ((float4*)(xnf + (size_t)wid * DIM))[lane] = o;
            ushort4 ob = make_ushort4(f2bf(o.x), f2bf(o.y), f2bf(o.z), f2bf(o.w));
            ((ushort4*)(xnb + (size_t)wid * DIM))[lane] = ob;
        }
    } else {
        const int c = wid - B_ROWS;
        if (c >= NCLS_PAD) return;
        if (c < NCLS) {
            const float* src = w + (size_t)c * DIM;
            float4 v = make_float4(0.f, 0.f, 0.f, 0.f);
            float s = 0.f;
            if (lane < 48) {
                v = ((const float4*)src)[lane];
                s = v.x * v.x + v.y * v.y + v.z * v.z + v.w * v.w;
            }
            #pragma unroll
            for (int off = 32; off > 0; off >>= 1) s += __shfl_xor(s, off);
            float inv = 1.0f / fmaxf(sqrtf(s), 1e-12f);
            if (lane == 0) winv[c] = inv;
            if (lane < 48) {
                ushort4 ob = make_ushort4(f2bf(v.x * inv), f2bf(v.y * inv),
                                          f2bf(v.z * inv), f2bf(v.w * inv));
                ((ushort4*)(wnb + (size_t)c * DIM))[lane] = ob;
            }
        } else {
            if (lane < 48)
                ((ushort4*)(wnb + (size_t)c * DIM))[lane] = make_ushort4(0, 0, 0, 0);
        }
    }
}

// ---------------------------------------------------------------------------
// MFMA GEMM + fused online-softmax/top-2 stats.
// grid (8 rowTiles, 784 classTiles), 256 threads (4 waves, each 64x64).
// LDS layout per operand: seg n (n=0..511) at n*16B holds T[row=n&127][k-chunk=n>>7]
// -> frag ds_read_b128 at (q*128+m)*16 is 2-way-bank (free) and matches the
// wave-uniform-base+lane*16 rule of global_load_lds.
// ---------------------------------------------------------------------------
__global__ __launch_bounds__(256, 3)
void gemm_stats_kernel(const unsigned short* __restrict__ xnb,
                       const unsigned short* __restrict__ wnb,
                       float4* __restrict__ pstats)
{
    __shared__ __align__(16) char lds[16384];
    const int tid  = threadIdx.x;
    const int wave = tid >> 6;
    const int lane = tid & 63;
    const int quad = lane >> 4;
    const int mrow = lane & 15;
    const int rowBase = blockIdx.x * BM;
    const int colBase = blockIdx.y * BN;
    const int rsel = 64 * (wave >> 1);   // wave's row offset in tile
    const int csel = 64 * (wave & 1);    // wave's col offset in tile

    floatx4 acc[4][4];
    #pragma unroll
    for (int i = 0; i < 4; ++i)
        #pragma unroll
        for (int j = 0; j < 4; ++j) {
            floatx4 z = {0.f, 0.f, 0.f, 0.f};
            acc[i][j] = z;
        }

    const int n0 = tid, n1 = tid + 256;
    const unsigned short* gA0 = xnb + (size_t)(rowBase + (n0 & 127)) * DIM + (n0 >> 7) * 8;
    const unsigned short* gA1 = xnb + (size_t)(rowBase + (n1 & 127)) * DIM + (n1 >> 7) * 8;
    const unsigned short* gB0 = wnb + (size_t)(colBase + (n0 & 127)) * DIM + (n0 >> 7) * 8;
    const unsigned short* gB1 = wnb + (size_t)(colBase + (n1 & 127)) * DIM + (n1 >> 7) * 8;
    char* lA0 = lds + (wave * 64) * 16;
    char* lA1 = lds + (256 + wave * 64) * 16;
    char* lB0 = lds + 8192 + (wave * 64) * 16;
    char* lB1 = lds + 8192 + (256 + wave * 64) * 16;

    #pragma unroll
    for (int ks = 0; ks < 6; ++ks) {
        const int k0 = ks * 32;
        gll16(gA0 + k0, lA0);
        gll16(gA1 + k0, lA1);
        gll16(gB0 + k0, lB0);
        gll16(gB1 + k0, lB1);
        __syncthreads();
        bf16x8 a[4], b[4];
        #pragma unroll
        for (int mi = 0; mi < 4; ++mi)
            a[mi] = *(const bf16x8*)(lds + (quad * 128 + rsel + mi * 16 + mrow) * 16);
        #pragma unroll
        for (int ni = 0; ni < 4; ++ni)
            b[ni] = *(const bf16x8*)(lds + 8192 + (quad * 128 + csel + ni * 16 + mrow) * 16);
        #pragma unroll
        for (int mi = 0; mi < 4; ++mi)
            #pragma unroll
            for (int ni = 0; ni < 4; ++ni)
                acc[mi][ni] = __builtin_amdgcn_mfma_f32_16x16x32_bf16(
                    a[mi], b[ni], acc[mi][ni], 0, 0, 0);
        __syncthreads();
    }

    // ---- epilogue: scale + pad-mask in place ----
    #pragma unroll
    for (int ni = 0; ni < 4; ++ni) {
        const int c = colBase + csel + 16 * ni + mrow;
        const bool ok = (c < NCLS);
        #pragma unroll
        for (int mi = 0; mi < 4; ++mi)
            #pragma unroll
            for (int r = 0; r < 4; ++r)
                acc[mi][ni][r] = ok ? acc[mi][ni][r] * S_SCALE : NEG_BIG;
    }

    // per-row (16 rows/lane-quad) max/top2/idx + sum-exp, quad butterfly
    float* red = (float*)(lds + wave * 1024);
    #pragma unroll
    for (int mi = 0; mi < 4; ++mi) {
        #pragma unroll
        for (int r = 0; r < 4; ++r) {
            float m = acc[mi][0][r];
            float v2 = NEG_BIG;
            int idx = colBase + csel + mrow;
            #pragma unroll
            for (int ni = 1; ni < 4; ++ni) {
                float v = acc[mi][ni][r];
                int c = colBase + csel + 16 * ni + mrow;
                if (v > m) { v2 = m; m = v; idx = c; }
                else v2 = fmaxf(v2, v);
            }
            #pragma unroll
            for (int off = 1; off < 16; off <<= 1) {
                float mo  = __shfl_xor(m, off);
                float v2o = __shfl_xor(v2, off);
                int   io  = __shfl_xor(idx, off);
                float nv2 = fmaxf(fminf(m, mo), fmaxf(v2, v2o));
                if (mo > m) { m = mo; idx = io; }
                v2 = nv2;
            }
            float l = 0.f;
            #pragma unroll
            for (int ni = 0; ni < 4; ++ni)
                l += __expf(acc[mi][ni][r] - m);
            #pragma unroll
            for (int off = 1; off < 16; off <<= 1)
                l += __shfl_xor(l, off);
            if (mrow == 0)
                ((float4*)red)[mi * 16 + quad * 4 + r] =
                    make_float4(m, l, v2, __int_as_float(idx));
        }
    }
    __syncthreads();
    // redistribute: lane L takes row-in-wave L -> coalesced float4 store
    float4 st = ((float4*)red)[lane];
    const int cc = blockIdx.y * 2 + (wave & 1);
    pstats[(size_t)cc * B_ROWS + rowBase + rsel + lane] = st;
}

// ---------------------------------------------------------------------------
// Tree merge stage 1: 1568 chunks -> 16 groups. grid (16, 16) x 64 threads.
// ---------------------------------------------------------------------------
__global__ __launch_bounds__(64)
void finalize1_kernel(const float4* __restrict__ pstats, float4* __restrict__ pstats2)
{
    const int g = blockIdx.x;
    const int r = blockIdx.y * 64 + threadIdx.x;
    float M = -INFINITY, L = 0.f, V2 = -INFINITY;
    int I = -1;
    const float4* p = pstats + (size_t)g * CCPG * B_ROWS + r;
    #pragma unroll 2
    for (int c = 0; c < CCPG; ++c)
        merge_stats(M, L, V2, I, p[(size_t)c * B_ROWS]);
    pstats2[(size_t)g * B_ROWS + r] = make_float4(M, L, V2, __int_as_float(I));
}

// ---------------------------------------------------------------------------
// Tree merge stage 2 + ArcFace margin correction + loss/prec1 accumulate.
// ---------------------------------------------------------------------------
__global__ __launch_bounds__(64)
void finalize2_kernel(const float4* __restrict__ pstats2,
                      const float* __restrict__ xnf, const float* __restrict__ w,
                      const float* __restrict__ winv, const int* __restrict__ label,
                      float* __restrict__ accum)
{
    const int r = blockIdx.x * 64 + threadIdx.x;
    float M = -INFINITY, L = 0.f, V2 = -INFINITY;
    int I = -1;
    #pragma unroll
    for (int g = 0; g < NGRP; ++g)
        merge_stats(M, L, V2, I, pstats2[(size_t)g * B_ROWS + r]);

    const int lab = label[r];
    const float4* xr = (const float4*)(xnf + (size_t)r * DIM);
    const float4* wr = (const float4*)(w + (size_t)lab * DIM);
    float dot = 0.f;
    #pragma unroll
    for (int q = 0; q < 48; ++q) {
        float4 a = xr[q], b = wr[q];
        dot += a.x * b.x + a.y * b.y + a.z * b.z + a.w * b.w;
    }
    float cosl    = dot * winv[lab];
    float t_plain = S_SCALE * cosl;
    float sine    = sqrtf(fmaxf(0.f, fminf(1.f, 1.f - cosl * cosl)));
    float phi     = cosl * COS_M - sine * SIN_M;
    float modv    = ((cosl - TH_C) > 0.f) ? phi : (cosl - MM_C);
    float t_mod   = S_SCALE * modv;

    float Ladj = L - __expf(t_plain - M) + __expf(t_mod - M);
    Ladj = fmaxf(Ladj, 1e-30f);
    float lse  = M + logf(Ladj);
    float loss = lse - t_mod;
    float corr = (I == lab && t_mod > V2) ? 1.f : 0.f;

    #pragma unroll
    for (int off = 32; off > 0; off >>= 1) {
        loss += __shfl_xor(loss, off);
        corr += __shfl_xor(corr, off);
    }
    if (threadIdx.x == 0) {
        atomicAdd(&accum[0], loss);
        atomicAdd(&accum[1], corr);
    }
}

__global__ void writeout_kernel(const float* __restrict__ accum, float* __restrict__ out)
{
    out[0] = accum[0] * (1.0f / (float)B_ROWS);
    out[1] = accum[1] * (100.0f / (float)B_ROWS);
}

// ---------------------------------------------------------------------------
extern "C" void kernel_launch(void* const* d_in, const int* in_sizes, int n_in,
                              void* d_out, int out_size, void* d_ws, size_t ws_size,
                              hipStream_t stream)
{
    const float* x     = (const float*)d_in[0];
    const float* w     = (const float*)d_in[1];
    const int*   label = (const int*)d_in[2];
    float* out = (float*)d_out;

    char* ws = (char*)d_ws;
    size_t off = 0;
    float* accum = (float*)(ws + off);           off += 256;
    float* xnf   = (float*)(ws + off);           off += (size_t)B_ROWS * DIM * 4;      // 786432
    float* winv  = (float*)(ws + off);           off += 400128;                         // 100000*4 padded
    unsigned short* xnb = (unsigned short*)(ws + off); off += (size_t)B_ROWS * DIM * 2; // 393216
    unsigned short* wnb = (unsigned short*)(ws + off); off += (size_t)NCLS_PAD * DIM * 2; // 38535168
    float4* pstats  = (float4*)(ws + off);       off += (size_t)NCHUNK * B_ROWS * 16;   // 25690112
    float4* pstats2 = (float4*)(ws + off);       off += (size_t)NGRP * B_ROWS * 16;     // 262144

    hipMemsetAsync(accum, 0, 2 * sizeof(float), stream);

    prep_kernel<<<dim3((B_ROWS + NCLS_PAD) / 4), dim3(256), 0, stream>>>(
        x, w, xnf, xnb, wnb, winv);
    gemm_stats_kernel<<<dim3(B_ROWS / BM, NTILE), dim3(256), 0, stream>>>(
        xnb, wnb, pstats);
    finalize1_kernel<<<dim3(NGRP, B_ROWS / 64), dim3(64), 0, stream>>>(pstats, pstats2);
    finalize2_kernel<<<dim3(B_ROWS / 64), dim3(64), 0, stream>>>(
        pstats2, xnf, w, winv, label, accum);
    writeout_kernel<<<dim3(1), dim3(1), 0, stream>>>(accum, out);
}

// Round 4
// 266.593 us; speedup vs baseline: 9.1262x; 1.1195x over previous
//
#include <hip/hip_runtime.h>
#include <math.h>

#define B_ROWS   1024
#define DIM      192
#define NCLS     100000
#define S_SCALE  30.0f
#define COS_M    0.98006657784124163f
#define SIN_M    0.19866933079506122f
#define TH_C     (-0.98006657784124163f)
#define MM_C     0.039733866159012243f
#define L2E30    43.2808512266689f      // 30 * log2(e)

#define NTILE_B    784     // 128-class tiles
#define CT_PER_BLK 8       // class tiles per gemm block
#define NCG        98      // class groups (784/8)
#define NCHUNK     196     // partial slots: NCG * 2 csel halves
#define NRT        8       // row tiles (1024/128)
#define SEGS_TILE  3072    // 24 k8-groups * 128 rows
#define TILE_BYTES 49152   // SEGS_TILE * 16

typedef float floatx4 __attribute__((ext_vector_type(4)));
typedef __bf16 bf16x8 __attribute__((ext_vector_type(8)));

__device__ __forceinline__ unsigned int f2bf(float x) {
    unsigned int u = __float_as_uint(x);
    u = (u + 0x7fffu + ((u >> 16) & 1u)) >> 16;   // RNE
    return u;
}
__device__ __forceinline__ unsigned int pack2(float lo, float hi) {
    return f2bf(lo) | (f2bf(hi) << 16);
}

__device__ __forceinline__ void gll16(const void* g, void* l) {
    __builtin_amdgcn_global_load_lds(
        (const __attribute__((address_space(1))) unsigned int*)g,
        (__attribute__((address_space(3))) unsigned int*)l, 16, 0, 0);
}

// ---------------------------------------------------------------------------
// Fused prep: L2-normalize + bf16-pack + MFMA-order swizzle in one pass.
// Blocks 0..783: B tiles from w (scaled by 1/||w||, pad rows zeroed, winv out).
// Blocks 784..791: A tiles from x (also writes fp32 xnf for finalize).
// Thread pair (2r, 2r+1) owns row r; each thread holds half a row (24 float4)
// in registers, so w is read exactly once.
// ---------------------------------------------------------------------------
__global__ __launch_bounds__(256)
void prep_kernel(const float* __restrict__ x, const float* __restrict__ w,
                 float* __restrict__ xnf, float* __restrict__ winv,
                 unsigned short* __restrict__ bsw, unsigned short* __restrict__ asw)
{
    const int b = blockIdx.x;
    const int t = threadIdx.x;
    const bool isB = (b < NTILE_B);
    const int r    = t >> 1;       // row within tile, 0..127
    const int half = t & 1;        // which half of the 192 floats
    const int rbase = isB ? b * 128 : (b - NTILE_B) * 128;
    const int row = rbase + r;
    unsigned short* dst = isB ? (bsw + (size_t)b * SEGS_TILE * 8)
                              : (asw + (size_t)(b - NTILE_B) * SEGS_TILE * 8);
    const bool live = isB ? (row < NCLS) : true;

    float4 buf[24];
    float s = 0.f;
    if (live) {
        const float4* sp = (const float4*)((isB ? w : x) + (size_t)row * DIM) + half * 24;
        #pragma unroll
        for (int q = 0; q < 24; ++q) {
            float4 v = sp[q];
            buf[q] = v;
            s += v.x * v.x + v.y * v.y + v.z * v.z + v.w * v.w;
        }
    }
    s += __shfl_xor(s, 1);
    const float inv = live ? (1.0f / fmaxf(sqrtf(s), 1e-12f)) : 0.0f;

    if (isB) {
        if (live && half == 0) winv[row] = inv;
    } else {
        float4* xd = (float4*)(xnf + (size_t)row * DIM) + half * 24;
        #pragma unroll
        for (int q = 0; q < 24; ++q)
            xd[q] = make_float4(buf[q].x * inv, buf[q].y * inv,
                                buf[q].z * inv, buf[q].w * inv);
    }

    // swizzled bf16 segs: seg = k8*128 + r, k8 = half*12 + j
    #pragma unroll
    for (int j = 0; j < 12; ++j) {
        const int k8 = half * 12 + j;
        uint4 o;
        if (live) {
            float4 a0 = buf[2 * j], a1 = buf[2 * j + 1];
            o.x = pack2(a0.x * inv, a0.y * inv);
            o.y = pack2(a0.z * inv, a0.w * inv);
            o.z = pack2(a1.x * inv, a1.y * inv);
            o.w = pack2(a1.z * inv, a1.w * inv);
        } else {
            o = make_uint4(0u, 0u, 0u, 0u);
        }
        *(uint4*)(dst + (size_t)(k8 * 128 + r) * 8) = o;
    }
}

// ---------------------------------------------------------------------------
// GEMM + fused fixed-base softmax stats. grid (8 rowtiles, 98 classgroups),
// 256 threads (4 waves, each a 64x64 quadrant), CT=8 class tiles per block.
// Per-lane running (max, sum); one butterfly per block; partials indexed by
// (classgroup, csel-half) -- waves 0/1 (and 2/3) cover DIFFERENT class halves
// of the SAME rows, so they get separate slots (the R3 bug).
// ---------------------------------------------------------------------------
__global__ __launch_bounds__(256, 3)
void gemm_stats_kernel(const unsigned short* __restrict__ asw,
                       const unsigned short* __restrict__ bsw,
                       float2* __restrict__ pstats)
{
    __shared__ __align__(16) char lds[32768];
    char* ldsA = lds;
    char* ldsB = lds + 16384;
    const int tid  = threadIdx.x;
    const int wave = tid >> 6;
    const int lane = tid & 63;
    const int quad = lane >> 4;
    const int mrow = lane & 15;
    const int rt = blockIdx.x;
    const int cg = blockIdx.y;
    const int rsel = 64 * (wave >> 1);
    const int csel = 64 * (wave & 1);
    const bool padblk = (cg == NCG - 1);

    const char* srcA  = (const char*)asw + (size_t)rt * TILE_BYTES;
    const char* srcB0 = (const char*)bsw + (size_t)cg * CT_PER_BLK * TILE_BYTES;

    float m_s[4][4], s_s[4][4];
    #pragma unroll
    for (int mi = 0; mi < 4; ++mi)
        #pragma unroll
        for (int r = 0; r < 4; ++r) { m_s[mi][r] = -2.0f; s_s[mi][r] = 0.f; }

    for (int ct = 0; ct < CT_PER_BLK; ++ct) {
        const char* srcB = srcB0 + (size_t)ct * TILE_BYTES;
        floatx4 acc[4][4];
        #pragma unroll
        for (int mi = 0; mi < 4; ++mi)
            #pragma unroll
            for (int ni = 0; ni < 4; ++ni) {
                floatx4 z = {0.f, 0.f, 0.f, 0.f};
                acc[mi][ni] = z;
            }

        #pragma unroll
        for (int ks = 0; ks < 3; ++ks) {
            #pragma unroll
            for (int q = 0; q < 4; ++q) {
                const int segoff = (q * 256 + tid) * 16;
                const int ldst   = (q * 256 + wave * 64) * 16;
                gll16(srcA + ks * 16384 + segoff, ldsA + ldst);
                gll16(srcB + ks * 16384 + segoff, ldsB + ldst);
            }
            __syncthreads();
            #pragma unroll
            for (int t2 = 0; t2 < 2; ++t2) {
                bf16x8 a[4], b[4];
                #pragma unroll
                for (int mi = 0; mi < 4; ++mi)
                    a[mi] = *(const bf16x8*)(ldsA +
                        (((t2 * 4 + quad) << 7) + rsel + mi * 16 + mrow) * 16);
                #pragma unroll
                for (int ni = 0; ni < 4; ++ni)
                    b[ni] = *(const bf16x8*)(ldsB +
                        (((t2 * 4 + quad) << 7) + csel + ni * 16 + mrow) * 16);
                #pragma unroll
                for (int mi = 0; mi < 4; ++mi)
                    #pragma unroll
                    for (int ni = 0; ni < 4; ++ni)
                        acc[mi][ni] = __builtin_amdgcn_mfma_f32_16x16x32_bf16(
                            a[mi], b[ni], acc[mi][ni], 0, 0, 0);
            }
            __syncthreads();
        }

        // epilogue: fixed-base-30 stats, per-lane only (1 fma + 1 exp2 + add + max)
        #pragma unroll
        for (int ni = 0; ni < 4; ++ni) {
            bool ok = true;
            if (padblk) {
                const int c = cg * 1024 + ct * 128 + csel + 16 * ni + mrow;
                ok = (c < NCLS);
            }
            #pragma unroll
            for (int mi = 0; mi < 4; ++mi)
                #pragma unroll
                for (int r = 0; r < 4; ++r) {
                    float v = ok ? acc[mi][ni][r] : -2.0f;
                    m_s[mi][r] = fmaxf(m_s[mi][r], v);
                    s_s[mi][r] += exp2f(fmaf(v, L2E30, -L2E30));
                }
        }
    }

    // once-per-block reduction over the 16 mrow lanes sharing each row
    #pragma unroll
    for (int mi = 0; mi < 4; ++mi)
        #pragma unroll
        for (int r = 0; r < 4; ++r) {
            float s = s_s[mi][r], m = m_s[mi][r];
            #pragma unroll
            for (int off = 1; off < 16; off <<= 1) {
                s += __shfl_xor(s, off);
                m = fmaxf(m, __shfl_xor(m, off));
            }
            if (mrow == 0) {
                const int gr = rt * 128 + rsel + mi * 16 + quad * 4 + r;
                const int cc = cg * 2 + (wave & 1);      // csel half gets its own slot
                pstats[(size_t)cc * B_ROWS + gr] = make_float2(m * S_SCALE, s);
            }
        }
}

// ---------------------------------------------------------------------------
// Finalize: merge 196 partials/row (plain adds -- fixed base), label-logit
// margin correction, loss + prec1 accumulation. 16 blocks x 64 threads.
// ---------------------------------------------------------------------------
__global__ __launch_bounds__(64)
void finalize_kernel(const float2* __restrict__ pstats,
                     const float* __restrict__ xnf, const float* __restrict__ w,
                     const float* __restrict__ winv, const int* __restrict__ label,
                     float* __restrict__ accum)
{
    const int r = blockIdx.x * 64 + threadIdx.x;
    float M = -1e30f, L = 0.f;
    #pragma unroll 4
    for (int g = 0; g < NCHUNK; ++g) {
        float2 p = pstats[(size_t)g * B_ROWS + r];
        M = fmaxf(M, p.x);
        L += p.y;
    }

    const int lab = label[r];
    const float4* xr = (const float4*)(xnf + (size_t)r * DIM);
    const float4* wr = (const float4*)(w + (size_t)lab * DIM);
    float dot = 0.f;
    #pragma unroll
    for (int q = 0; q < 48; ++q) {
        float4 a = xr[q], b = wr[q];
        dot += a.x * b.x + a.y * b.y + a.z * b.z + a.w * b.w;
    }
    float cosl    = dot * winv[lab];
    float t_plain = S_SCALE * cosl;
    float sine    = sqrtf(fmaxf(0.f, fminf(1.f, 1.f - cosl * cosl)));
    float phi     = cosl * COS_M - sine * SIN_M;
    float modv    = ((cosl - TH_C) > 0.f) ? phi : (cosl - MM_C);
    float t_mod   = S_SCALE * modv;

    // swap plain label term for modified one (base-30 domain)
    float Ladj = L - __expf(t_plain - 30.0f) + __expf(t_mod - 30.0f);
    Ladj = fmaxf(Ladj, 1e-37f);
    float lse  = 30.0f + logf(Ladj);
    float loss = lse - t_mod;
    float corr = (t_mod > M) ? 1.f : 0.f;

    #pragma unroll
    for (int off = 32; off > 0; off >>= 1) {
        loss += __shfl_xor(loss, off);
        corr += __shfl_xor(corr, off);
    }
    if (threadIdx.x == 0) {
        atomicAdd(&accum[0], loss);
        atomicAdd(&accum[1], corr);
    }
}

__global__ void writeout_kernel(const float* __restrict__ accum, float* __restrict__ out)
{
    out[0] = accum[0] * (1.0f / (float)B_ROWS);
    out[1] = accum[1] * (100.0f / (float)B_ROWS);
}

// ---------------------------------------------------------------------------
extern "C" void kernel_launch(void* const* d_in, const int* in_sizes, int n_in,
                              void* d_out, int out_size, void* d_ws, size_t ws_size,
                              hipStream_t stream)
{
    const float* x     = (const float*)d_in[0];
    const float* w     = (const float*)d_in[1];
    const int*   label = (const int*)d_in[2];
    float* out = (float*)d_out;

    char* ws = (char*)d_ws;
    size_t off = 0;
    float* accum = (float*)(ws + off);                 off += 256;
    float* xnf   = (float*)(ws + off);                 off += (size_t)B_ROWS * DIM * 4;     // 786432
    float* winv  = (float*)(ws + off);                 off += 400128;
    unsigned short* asw = (unsigned short*)(ws + off); off += (size_t)NRT * TILE_BYTES;      // 393216
    unsigned short* bsw = (unsigned short*)(ws + off); off += (size_t)NTILE_B * TILE_BYTES;  // 38535168
    float2* pstats = (float2*)(ws + off);              off += (size_t)NCHUNK * B_ROWS * 8;   // 1605632

    hipMemsetAsync(accum, 0, 2 * sizeof(float), stream);

    prep_kernel<<<dim3(NTILE_B + NRT), dim3(256), 0, stream>>>(
        x, w, xnf, winv, bsw, asw);
    gemm_stats_kernel<<<dim3(NRT, NCG), dim3(256), 0, stream>>>(asw, bsw, pstats);
    finalize_kernel<<<dim3(B_ROWS / 64), dim3(64), 0, stream>>>(
        pstats, xnf, w, winv, label, accum);
    writeout_kernel<<<dim3(1), dim3(1), 0, stream>>>(accum, out);
}